// Round 5
// baseline (264.377 us; speedup 1.0000x reference)
//
#include <hip/hip_runtime.h>

#define D 128

typedef __attribute__((ext_vector_type(8))) short bf16x8;
typedef __attribute__((ext_vector_type(4))) float f32x4;
typedef __attribute__((ext_vector_type(2))) float f32x2;
typedef __attribute__((ext_vector_type(2))) uint  u32x2;

__device__ __forceinline__ ushort f2bf(float f) {   // round-to-nearest-even
    unsigned u = __float_as_uint(f);
    u += 0x7fffu + ((u >> 16) & 1u);
    return (ushort)(u >> 16);
}
__device__ __forceinline__ float bf2f(ushort h) {
    return __uint_as_float(((unsigned)h) << 16);
}

// ---------------------------------------------------------------------------
// XW(bf16) = X(fp32) @ W(fp32), one kernel. Each block converts W into
// fragment-ordered LDS itself (64KB fp32 read/block, L2-resident), then
// MFMA 16x16x32 bf16 with operands swapped (A=W frag, B=X frag):
//   D: lane&15 = XW row, (lane>>4)*4+reg = 4 consecutive XW cols.
// Fragment order: Wl[((jt*4+ks)*64 + lane)*8 + j] = W[k][c],
//   c = jt*16 + (lane&15), k = ks*32 + (lane>>4)*8 + j
// => identical layout to the round-4 (passing) Wf buffer.
// ---------------------------------------------------------------------------
__global__ __launch_bounds__(256) void gemm_mfma(const float* __restrict__ X,
                                                 const float* __restrict__ W,
                                                 ushort* __restrict__ XW, int M) {
    __shared__ ushort Wl[16384];   // 32KB, fragment-ordered, linear

    const int t = threadIdx.x;
    // --- W conversion: thread t owns column c = t&127, k8-groups half,+2,... ---
    {
        const int c = t & 127, half = t >> 7;
        const int jt = c >> 4;
#pragma unroll
        for (int g = 0; g < 8; ++g) {
            const int k8   = half + g * 2;          // 0..15 (k8 = k>>3)
            const int ks   = k8 >> 2;
            const int lsub = (k8 & 3) * 16 + (c & 15);   // lane
            uint4 pk;
            ushort tmp[8];
#pragma unroll
            for (int j = 0; j < 8; ++j)              // coalesced across c
                tmp[j] = f2bf(W[(k8 * 8 + j) * D + c]);
            pk.x = (uint)tmp[0] | ((uint)tmp[1] << 16);
            pk.y = (uint)tmp[2] | ((uint)tmp[3] << 16);
            pk.z = (uint)tmp[4] | ((uint)tmp[5] << 16);
            pk.w = (uint)tmp[6] | ((uint)tmp[7] << 16);
            *(uint4*)&Wl[(((jt * 4 + ks) * 64) + lsub) * 8] = pk;   // ds_write_b128
        }
    }

    const int lane = t & 63, wid = t >> 6;
    const int r0 = blockIdx.x * 64 + wid * 16;

    // --- X fragments (issued before the barrier; independent of LDS) ---
    int arow = r0 + (lane & 15);
    if (arow >= M) arow = M - 1;                 // clamp; stores guarded
    const float* xp = X + (size_t)arow * D + ((lane >> 4) * 8);

    bf16x8 xf[4];
#pragma unroll
    for (int ks = 0; ks < 4; ++ks) {
        float4 f0 = *(const float4*)(xp + ks * 32);
        float4 f1 = *(const float4*)(xp + ks * 32 + 4);
        bf16x8 av;
        av[0] = (short)f2bf(f0.x); av[1] = (short)f2bf(f0.y);
        av[2] = (short)f2bf(f0.z); av[3] = (short)f2bf(f0.w);
        av[4] = (short)f2bf(f1.x); av[5] = (short)f2bf(f1.y);
        av[6] = (short)f2bf(f1.z); av[7] = (short)f2bf(f1.w);
        xf[ks] = av;
    }

    __syncthreads();

    const bf16x8* wl = (const bf16x8*)Wl + lane;   // + (jt*4+ks)*64

    f32x4 acc[8];
#pragma unroll
    for (int jt = 0; jt < 8; ++jt) acc[jt] = (f32x4){0.f, 0.f, 0.f, 0.f};

#pragma unroll
    for (int jt = 0; jt < 8; ++jt)
#pragma unroll
        for (int ks = 0; ks < 4; ++ks) {
            bf16x8 w = wl[(jt * 4 + ks) * 64];     // ds_read_b128, conflict-free
            acc[jt] = __builtin_amdgcn_mfma_f32_16x16x32_bf16(w, xf[ks],
                                                              acc[jt], 0, 0, 0);
        }

    const int row = r0 + (lane & 15);
    if (row < M) {
        uint* dst = (uint*)XW + (size_t)row * 64 + (lane >> 4) * 2;
#pragma unroll
        for (int jt = 0; jt < 8; ++jt) {           // 8B stores, aligned
            u32x2 pv;
            pv[0] = (uint)f2bf(acc[jt][0]) | ((uint)f2bf(acc[jt][1]) << 16);
            pv[1] = (uint)f2bf(acc[jt][2]) | ((uint)f2bf(acc[jt][3]) << 16);
            *(u32x2*)(dst + jt * 8) = pv;
        }
    }
}

// ---------------------------------------------------------------------------
// CSR SpMM with fused row-bound search. One wave per output row; lane owns
// 2 bf16 cols (4B gather/lane, 256B/edge coalesced). Unroll-8 with clamped
// tail (repeat edge e-1 with v=0: L1-hit, exact). Non-temporal out stores.
// ---------------------------------------------------------------------------
__global__ __launch_bounds__(256) void spmm_csr(const ushort* __restrict__ XW,
                                                const int* __restrict__ rows,
                                                const int* __restrict__ cols,
                                                const float* __restrict__ vals,
                                                float* __restrict__ out,
                                                int N, int E) {
    const int lane = threadIdx.x & 63;
    const int r = blockIdx.x * 4 + (threadIdx.x >> 6);
    if (r >= N) return;

    // lower_bound over sorted rows: lane 0 -> r, lanes 1..63 -> r+1.
    int tgt = r + (lane != 0);
    int lo = 0, hi = E;
    while (lo < hi) {                       // <=21 iters, lanes nearly uniform
        int mid = (lo + hi) >> 1;
        if (rows[mid] < tgt) lo = mid + 1; else hi = mid;
    }
    const int s = __shfl(lo, 0);
    const int e = __shfl(lo, 1);

    const uint* base = (const uint*)XW;     // elem c*64 + lane = 2 bf16 cols
    float ax = 0.f, ay = 0.f;

    for (int i = s; i < e; i += 8) {
        int c[8]; float v[8]; uint u[8];
#pragma unroll
        for (int q = 0; q < 8; ++q) {
            int idx = i + q;
            int ci  = idx < e ? idx : e - 1;        // clamp (loop => e > s >= 0)
            c[q] = cols[ci];
            v[q] = idx < e ? vals[ci] : 0.f;
        }
#pragma unroll
        for (int q = 0; q < 8; ++q)                  // 8 gathers in flight
            u[q] = base[(size_t)c[q] * 64 + lane];
#pragma unroll
        for (int q = 0; q < 8; ++q) {
            ax += v[q] * bf2f((ushort)(u[q] & 0xffff));
            ay += v[q] * bf2f((ushort)(u[q] >> 16));
        }
    }
    f32x2 o; o[0] = ax; o[1] = ay;
    __builtin_nontemporal_store(o, (f32x2*)out + (size_t)r * 64 + lane);
}

// ---------------------------------------------------------------------------
extern "C" void kernel_launch(void* const* d_in, const int* in_sizes, int n_in,
                              void* d_out, int out_size, void* d_ws, size_t ws_size,
                              hipStream_t stream) {
    const float* X    = (const float*)d_in[0];
    const float* W    = (const float*)d_in[1];
    const int*   rows = (const int*)d_in[2];
    const int*   cols = (const int*)d_in[3];
    const float* vals = (const float*)d_in[4];
    float*       out  = (float*)d_out;

    const int M = in_sizes[0] / D;      // 100000 nodes
    const int E = in_sizes[2];          // 1600000 edges

    ushort* XWb = (ushort*)d_ws;        // 25.6MB scratch, fully overwritten

    gemm_mfma<<<(M + 63) / 64, 256, 0, stream>>>(X, W, XWb, M);
    spmm_csr <<<(M + 3) / 4, 256, 0, stream>>>(XWb, rows, cols, vals, out, M, E);
}

// Round 6
// 198.251 us; speedup vs baseline: 1.3335x; 1.3335x over previous
//
#include <hip/hip_runtime.h>

#define D 128

typedef __attribute__((ext_vector_type(8))) short bf16x8;
typedef __attribute__((ext_vector_type(4))) float f32x4;
typedef __attribute__((ext_vector_type(2))) float f32x2;
typedef __attribute__((ext_vector_type(2))) uint  u32x2;

__device__ __forceinline__ ushort f2bf(float f) {   // round-to-nearest-even
    unsigned u = __float_as_uint(f);
    u += 0x7fffu + ((u >> 16) & 1u);
    return (ushort)(u >> 16);
}
__device__ __forceinline__ float bf2f(ushort h) {
    return __uint_as_float(((unsigned)h) << 16);
}

// ---------------------------------------------------------------------------
// XW(bf16) = X(fp32) @ W(fp32) + fused row_ptr build.
//  * one global-thread-per-row binary search over sorted rows -> rp[] (100k
//    searches total, hidden under the block's independent W/X work)
//  * W converted to fragment-ordered LDS per block (layout verified r4/r5):
//    Wl[((jt*4+ks)*64 + lane)*8 + j] = W[k][c], c=jt*16+(lane&15),
//    k=ks*32+(lane>>4)*8+j
//  * MFMA 16x16x32 bf16, operands swapped (A=W frag, B=X frag):
//    D: lane&15 = XW row, (lane>>4)*4+reg = 4 consecutive XW cols.
// ---------------------------------------------------------------------------
__global__ __launch_bounds__(256) void gemm_mfma(const float* __restrict__ X,
                                                 const float* __restrict__ W,
                                                 const int* __restrict__ rows,
                                                 int E,
                                                 ushort* __restrict__ XW,
                                                 int* __restrict__ rp, int M) {
    __shared__ ushort Wl[16384];   // 32KB, fragment-ordered, linear

    const int t = threadIdx.x;

    // --- fused row_ptr: thread g does lower_bound(rows, g), g in [0, M] ---
    {
        const int g = blockIdx.x * 256 + t;
        if (g <= M) {
            int lo = 0, hi = E;
            while (lo < hi) {
                int mid = (lo + hi) >> 1;
                if (rows[mid] < g) lo = mid + 1; else hi = mid;
            }
            rp[g] = lo;
        }
    }

    // --- W conversion into fragment-ordered LDS ---
    {
        const int c = t & 127, half = t >> 7;
        const int jt = c >> 4;
#pragma unroll
        for (int g = 0; g < 8; ++g) {
            const int k8   = half + g * 2;               // 0..15 (k8 = k>>3)
            const int ks   = k8 >> 2;
            const int lsub = (k8 & 3) * 16 + (c & 15);   // lane
            uint4 pk;
            ushort tmp[8];
#pragma unroll
            for (int j = 0; j < 8; ++j)                  // coalesced across c
                tmp[j] = f2bf(W[(k8 * 8 + j) * D + c]);
            pk.x = (uint)tmp[0] | ((uint)tmp[1] << 16);
            pk.y = (uint)tmp[2] | ((uint)tmp[3] << 16);
            pk.z = (uint)tmp[4] | ((uint)tmp[5] << 16);
            pk.w = (uint)tmp[6] | ((uint)tmp[7] << 16);
            *(uint4*)&Wl[(((jt * 4 + ks) * 64) + lsub) * 8] = pk;
        }
    }

    const int lane = t & 63, wid = t >> 6;
    const int r0 = blockIdx.x * 64 + wid * 16;

    // --- X fragments (independent of LDS; issued before barrier) ---
    int arow = r0 + (lane & 15);
    if (arow >= M) arow = M - 1;                 // clamp; stores guarded
    const float* xp = X + (size_t)arow * D + ((lane >> 4) * 8);

    bf16x8 xf[4];
#pragma unroll
    for (int ks = 0; ks < 4; ++ks) {
        float4 f0 = *(const float4*)(xp + ks * 32);
        float4 f1 = *(const float4*)(xp + ks * 32 + 4);
        bf16x8 av;
        av[0] = (short)f2bf(f0.x); av[1] = (short)f2bf(f0.y);
        av[2] = (short)f2bf(f0.z); av[3] = (short)f2bf(f0.w);
        av[4] = (short)f2bf(f1.x); av[5] = (short)f2bf(f1.y);
        av[6] = (short)f2bf(f1.z); av[7] = (short)f2bf(f1.w);
        xf[ks] = av;
    }

    __syncthreads();

    const bf16x8* wl = (const bf16x8*)Wl + lane;   // + (jt*4+ks)*64

    f32x4 acc[8];
#pragma unroll
    for (int jt = 0; jt < 8; ++jt) acc[jt] = (f32x4){0.f, 0.f, 0.f, 0.f};

#pragma unroll
    for (int jt = 0; jt < 8; ++jt)
#pragma unroll
        for (int ks = 0; ks < 4; ++ks) {
            bf16x8 w = wl[(jt * 4 + ks) * 64];     // ds_read_b128, conflict-free
            acc[jt] = __builtin_amdgcn_mfma_f32_16x16x32_bf16(w, xf[ks],
                                                              acc[jt], 0, 0, 0);
        }

    const int row = r0 + (lane & 15);
    if (row < M) {
        uint* dst = (uint*)XW + (size_t)row * 64 + (lane >> 4) * 2;
#pragma unroll
        for (int jt = 0; jt < 8; ++jt) {           // 8B stores, aligned
            u32x2 pv;
            pv[0] = (uint)f2bf(acc[jt][0]) | ((uint)f2bf(acc[jt][1]) << 16);
            pv[1] = (uint)f2bf(acc[jt][2]) | ((uint)f2bf(acc[jt][3]) << 16);
            *(u32x2*)(dst + jt * 8) = pv;
        }
    }
}

// ---------------------------------------------------------------------------
// CSR SpMM, two rows per wave: joint unroll-4 over both rows = 8 independent
// gathers in flight per wave, no clamp waste. Lane owns 2 bf16 cols (4B
// gather/lane, 256B/edge). NT loads for streamed cols/vals; NT out stores.
// ---------------------------------------------------------------------------
__global__ __launch_bounds__(256) void spmm_csr(const ushort* __restrict__ XW,
                                                const int* __restrict__ rp,
                                                const int* __restrict__ cols,
                                                const float* __restrict__ vals,
                                                float* __restrict__ out, int N) {
    const int lane = threadIdx.x & 63;
    const int ra = blockIdx.x * 8 + (threadIdx.x >> 6) * 2;   // rows ra, ra+1
    if (ra >= N) return;
    const bool has_b = (ra + 1) < N;

    const int sa = rp[ra];
    const int ea = rp[ra + 1];
    const int eb = has_b ? rp[ra + 2] : ea;

    const uint* base = (const uint*)XW;     // elem c*64 + lane = 2 bf16 cols
    float axa = 0.f, aya = 0.f, axb = 0.f, ayb = 0.f;

    int ia = sa, ib = ea;                   // row b starts at ea

    // joint main loop: 8 gathers in flight (4 per row, independent chains)
    while (ia + 4 <= ea && ib + 4 <= eb) {
        int c0[4], c1[4]; float v0[4], v1[4]; uint u0[4], u1[4];
#pragma unroll
        for (int q = 0; q < 4; ++q) {
            c0[q] = __builtin_nontemporal_load(&cols[ia + q]);
            c1[q] = __builtin_nontemporal_load(&cols[ib + q]);
            v0[q] = __builtin_nontemporal_load(&vals[ia + q]);
            v1[q] = __builtin_nontemporal_load(&vals[ib + q]);
        }
#pragma unroll
        for (int q = 0; q < 4; ++q) {
            u0[q] = base[(size_t)c0[q] * 64 + lane];
            u1[q] = base[(size_t)c1[q] * 64 + lane];
        }
#pragma unroll
        for (int q = 0; q < 4; ++q) {
            axa += v0[q] * bf2f((ushort)(u0[q] & 0xffff));
            aya += v0[q] * bf2f((ushort)(u0[q] >> 16));
            axb += v1[q] * bf2f((ushort)(u1[q] & 0xffff));
            ayb += v1[q] * bf2f((ushort)(u1[q] >> 16));
        }
        ia += 4; ib += 4;
    }
    // drain row a
    for (; ia + 4 <= ea; ia += 4) {
        int c[4]; float v[4]; uint u[4];
#pragma unroll
        for (int q = 0; q < 4; ++q) {
            c[q] = __builtin_nontemporal_load(&cols[ia + q]);
            v[q] = __builtin_nontemporal_load(&vals[ia + q]);
        }
#pragma unroll
        for (int q = 0; q < 4; ++q) u[q] = base[(size_t)c[q] * 64 + lane];
#pragma unroll
        for (int q = 0; q < 4; ++q) {
            axa += v[q] * bf2f((ushort)(u[q] & 0xffff));
            aya += v[q] * bf2f((ushort)(u[q] >> 16));
        }
    }
    for (; ia < ea; ++ia) {
        int c = cols[ia]; float v = vals[ia];
        uint u = base[(size_t)c * 64 + lane];
        axa += v * bf2f((ushort)(u & 0xffff));
        aya += v * bf2f((ushort)(u >> 16));
    }
    // drain row b
    for (; ib + 4 <= eb; ib += 4) {
        int c[4]; float v[4]; uint u[4];
#pragma unroll
        for (int q = 0; q < 4; ++q) {
            c[q] = __builtin_nontemporal_load(&cols[ib + q]);
            v[q] = __builtin_nontemporal_load(&vals[ib + q]);
        }
#pragma unroll
        for (int q = 0; q < 4; ++q) u[q] = base[(size_t)c[q] * 64 + lane];
#pragma unroll
        for (int q = 0; q < 4; ++q) {
            axb += v[q] * bf2f((ushort)(u[q] & 0xffff));
            ayb += v[q] * bf2f((ushort)(u[q] >> 16));
        }
    }
    for (; ib < eb; ++ib) {
        int c = cols[ib]; float v = vals[ib];
        uint u = base[(size_t)c * 64 + lane];
        axb += v * bf2f((ushort)(u & 0xffff));
        ayb += v * bf2f((ushort)(u >> 16));
    }

    f32x2 oa; oa[0] = axa; oa[1] = aya;
    __builtin_nontemporal_store(oa, (f32x2*)out + (size_t)ra * 64 + lane);
    if (has_b) {
        f32x2 ob; ob[0] = axb; ob[1] = ayb;
        __builtin_nontemporal_store(ob, (f32x2*)out + (size_t)(ra + 1) * 64 + lane);
    }
}

// ---------------------------------------------------------------------------
extern "C" void kernel_launch(void* const* d_in, const int* in_sizes, int n_in,
                              void* d_out, int out_size, void* d_ws, size_t ws_size,
                              hipStream_t stream) {
    const float* X    = (const float*)d_in[0];
    const float* W    = (const float*)d_in[1];
    const int*   rows = (const int*)d_in[2];
    const int*   cols = (const int*)d_in[3];
    const float* vals = (const float*)d_in[4];
    float*       out  = (float*)d_out;

    const int M = in_sizes[0] / D;      // 100000 nodes
    const int E = in_sizes[2];          // 1600000 edges

    // Workspace: [0, 25.6MB) XW bf16; then row_ptr int[M+1].
    ushort* XWb = (ushort*)d_ws;
    int*    rp  = (int*)((char*)d_ws + (size_t)M * D * sizeof(ushort));

    gemm_mfma<<<(M + 63) / 64, 256, 0, stream>>>(X, W, rows, E, XWb, rp, M);
    spmm_csr <<<(M + 7) / 8, 256, 0, stream>>>(XWb, rp, cols, vals, out, M);
}